// Round 7
// baseline (111.813 us; speedup 1.0000x reference)
//
#include <hip/hip_runtime.h>

#define NB   4
#define CO   16
#define PH   7
#define PW   7
#define SR   2
#define HH   80
#define WW   80
#define NROI 512
#define CIJ  (CO*PH*PW)   // 784
#define PLANE (HH*WW)     // 6400 floats = 25.6 KB
#define NF4  (PLANE/4)    // 1600

typedef float f4v __attribute__((ext_vector_type(4), aligned(16)));

typedef __attribute__((address_space(1))) const void gvoid_t;
typedef __attribute__((address_space(3))) void svoid_t;

// d_ws layout:
//   [0]    int   base[8]
//   [64]   u16   order[512]
//   [2048] f4v   geom[512]   (x1, y1, bin_w, bin_h)
#define WS_ORDER_OFF 64
#define WS_GEOM_OFF  2048

// ---- pre-kernel: compact ROIs by batch, precompute geometry (1 block) ----
__global__ __launch_bounds__(512) void psroi_prep_kernel(
    const float* __restrict__ rois, int* __restrict__ base,
    unsigned short* __restrict__ order, f4v* __restrict__ geom)
{
    __shared__ int cnt[NB];
    __shared__ int cbase[NB + 1];
    int n = threadIdx.x;
    if (n < NB) cnt[n] = 0;
    __syncthreads();
    int b = (int)rois[n * 5 + 0];
    int rank = atomicAdd(&cnt[b], 1);
    __syncthreads();
    if (n == 0) {
        cbase[0] = 0;
        for (int k = 0; k < NB; ++k) cbase[k + 1] = cbase[k] + cnt[k];
        for (int k = 0; k <= NB; ++k) base[k] = cbase[k];
    }
    __syncthreads();
    int pos = cbase[b] + rank;
    order[pos] = (unsigned short)n;

    float x1 = rois[n * 5 + 1] * (float)WW;
    float y1 = rois[n * 5 + 2] * (float)HH;
    float x2 = rois[n * 5 + 3] * (float)WW;
    float y2 = rois[n * 5 + 4] * (float)HH;
    f4v g;
    g.x = x1;
    g.y = y1;
    g.z = fmaxf(x2 - x1, 0.1f) * (1.0f / PW);   // bin_w
    g.w = fmaxf(y2 - y1, 0.1f) * (1.0f / PH);   // bin_h
    geom[pos] = g;
}

// ---- main kernel: one block per (cij, b) ----
// Staging: 7 x global_load_lds dwordx4 per wave (direct HBM/L3 -> LDS DMA,
// no VGPR round trip, no ds_write). Gather: lane pair (2i, 2i+1) handles one
// ROI, one sy-row each; combine via shfl_xor. All 256 lanes active.
__global__ __launch_bounds__(256) void psroi_main_kernel(
    const float* __restrict__ feat,   // [B, CIJ, H, W]
    const int* __restrict__ base,
    const unsigned short* __restrict__ order,
    const f4v* __restrict__ geom,
    float* __restrict__ out)          // [N, CO, PH, PW]
{
    __shared__ __align__(16) float sp[PLANE];

    int u   = blockIdx.x;       // cij*4 + b
    int cij = u >> 2;
    int b   = u & 3;
    int rem = cij % (PH * PW);
    int i = rem / PW;
    int j = rem % PW;
    int n = threadIdx.x;

    // ---- stage plane (b, cij) via global_load_lds (16B/lane) ----
    const f4v* src = (const f4v*)(feat + ((size_t)b * CIJ + (size_t)cij) * PLANE);
    int wbase = n & ~63;        // wave-uniform element base (f4 units)
    #pragma unroll
    for (int it = 0; it < 6; ++it) {
        const f4v* g = src + it * 256 + n;                 // per-lane global
        float* l = sp + (size_t)(it * 256 + wbase) * 4;    // wave-uniform LDS base
        __builtin_amdgcn_global_load_lds((gvoid_t*)g, (svoid_t*)l, 16, 0, 0);
    }
    if (n < 64) {               // tail: 1536..1599 (wave 0 only)
        const f4v* g = src + 1536 + n;
        float* l = sp + (size_t)1536 * 4;
        __builtin_amdgcn_global_load_lds((gvoid_t*)g, (svoid_t*)l, 16, 0, 0);
    }

    int lo = base[b];
    int hi = base[b + 1];

    __syncthreads();            // drains vmcnt(0): LDS holds the plane

    int sy = n & 1;
    float sy_off = ((float)sy + 0.5f) * (1.0f / SR);

    for (int t = lo + (n >> 1); t < hi; t += 128) {
        int m = (int)order[t];
        f4v g = geom[t];
        float x1 = g.x, y1 = g.y, bin_w = g.z, bin_h = g.w;

        // one sy-row per lane
        float ys = y1 + ((float)i + sy_off) * bin_h;
        bool ymask = (ys >= -1.0f) && (ys <= (float)HH);
        float yc = fminf(fmaxf(ys, 0.0f), (float)(HH - 1));
        int   y0 = (int)floorf(yc);
        int   y1i = min(y0 + 1, HH - 1);
        float ly = yc - (float)y0, hy = 1.0f - ly;

        float partial = 0.0f;
        #pragma unroll
        for (int sx = 0; sx < SR; ++sx) {
            float xs = x1 + ((float)j + ((float)sx + 0.5f) * (1.0f / SR)) * bin_w;
            bool xmask = (xs >= -1.0f) && (xs <= (float)WW);
            float xc = fminf(fmaxf(xs, 0.0f), (float)(WW - 1));
            int   x0 = (int)floorf(xc);
            int   x0c = min(x0, WW - 2);   // x0==79 -> lx==0, shifted pair exact
            bool  sh = (x0 != x0c);
            float lx = xc - (float)x0, hx = 1.0f - lx;

            float t0 = sp[y0  * WW + x0c], t1 = sp[y0  * WW + x0c + 1];
            float b0 = sp[y1i * WW + x0c], b1 = sp[y1i * WW + x0c + 1];

            float v00 = sh ? t1 : t0;
            float v10 = sh ? b1 : b0;
            float v = (v00 * hx + t1 * lx) * hy + (v10 * hx + b1 * lx) * ly;
            if (ymask && xmask) partial += v;
        }

        float other = __shfl_xor(partial, 1);
        if (sy == 0)
            out[(size_t)m * CIJ + cij] = (partial + other) * 0.25f;
    }
}

extern "C" void kernel_launch(void* const* d_in, const int* in_sizes, int n_in,
                              void* d_out, int out_size, void* d_ws, size_t ws_size,
                              hipStream_t stream)
{
    const float* feat = (const float*)d_in[0];
    const float* rois = (const float*)d_in[1];
    float* out = (float*)d_out;

    char* ws = (char*)d_ws;
    int* base = (int*)ws;
    unsigned short* order = (unsigned short*)(ws + WS_ORDER_OFF);
    f4v* geom = (f4v*)(ws + WS_GEOM_OFF);

    psroi_prep_kernel<<<1, NROI, 0, stream>>>(rois, base, order, geom);
    psroi_main_kernel<<<CIJ * NB, 256, 0, stream>>>(feat, base, order, geom, out);
}